// Round 10
// baseline (24.112 us; speedup 1.0000x reference)
//
#include <hip/hip_runtime.h>

constexpr int IMG_H = 2048;
constexpr int IMG_W = 2048;
constexpr int TW = 128;        // output tile width (cols) per block
constexpr int TH = 16;         // output tile height (rows) per block
constexpr int LC = TW + 4;     // staged cols (132)
constexpr int LR = TH + 4;     // staged rows (20)

// compare-exchange: a=min, b=max (2 VALU)
#define CE(a, b) {                                              \
    float _mn, _mx;                                             \
    asm("v_min_f32 %0, %1, %2" : "=v"(_mn) : "v"(a), "v"(b));   \
    asm("v_max_f32 %0, %1, %2" : "=v"(_mx) : "v"(a), "v"(b));   \
    a = _mn; b = _mx;                                           \
}

// 3-element sort via VOP3 3-input ops: a=min, b=med, c=max (3 VALU)
#define SORT3(a, b, c) {                                                      \
    float _n, _d, _x;                                                         \
    asm("v_min3_f32 %0, %1, %2, %3" : "=v"(_n) : "v"(a), "v"(b), "v"(c));     \
    asm("v_med3_f32 %0, %1, %2, %3" : "=v"(_d) : "v"(a), "v"(b), "v"(c));     \
    asm("v_max3_f32 %0, %1, %2, %3" : "=v"(_x) : "v"(a), "v"(b), "v"(c));     \
    a = _n; b = _d; c = _x;                                                   \
}

__device__ __forceinline__ void sw14(float& a0, float& a1, float& a2, float& a3, float& a4,
                                     float& a5, float& a6, float& a7, float& a8, float& a9,
                                     float& a10, float& a11, float& a12, float& a13) {
    SORT3(a0, a1, a2) SORT3(a3, a4, a5) SORT3(a6, a7, a8) SORT3(a9, a10, a11) CE(a12, a13)
    SORT3(a0, a3, a6) SORT3(a0, a9, a12)
    SORT3(a2, a5, a8) SORT3(a8, a11, a13)
}
__device__ __forceinline__ void sw13(float& a0, float& a1, float& a2, float& a3, float& a4,
                                     float& a5, float& a6, float& a7, float& a8, float& a9,
                                     float& a10, float& a11, float& a12) {
    SORT3(a0, a1, a2) SORT3(a3, a4, a5) SORT3(a6, a7, a8) SORT3(a9, a10, a11)
    SORT3(a0, a3, a6) SORT3(a0, a9, a12)
    SORT3(a2, a5, a8) SORT3(a8, a11, a12)
}
__device__ __forceinline__ void sw12(float& a0, float& a1, float& a2, float& a3, float& a4,
                                     float& a5, float& a6, float& a7, float& a8, float& a9,
                                     float& a10, float& a11) {
    SORT3(a0, a1, a2) SORT3(a3, a4, a5) SORT3(a6, a7, a8) SORT3(a9, a10, a11)
    SORT3(a0, a3, a6) CE(a0, a9)
    SORT3(a2, a5, a8) CE(a8, a11)
}
__device__ __forceinline__ void sw11(float& a0, float& a1, float& a2, float& a3, float& a4,
                                     float& a5, float& a6, float& a7, float& a8, float& a9,
                                     float& a10) {
    SORT3(a0, a1, a2) SORT3(a3, a4, a5) SORT3(a6, a7, a8) CE(a9, a10)
    SORT3(a0, a3, a6) CE(a0, a9)
    SORT3(a2, a5, a8) CE(a8, a10)
}
__device__ __forceinline__ void sw10(float& a0, float& a1, float& a2, float& a3, float& a4,
                                     float& a5, float& a6, float& a7, float& a8, float& a9) {
    SORT3(a0, a1, a2) SORT3(a3, a4, a5) SORT3(a6, a7, a8)
    SORT3(a0, a3, a6) CE(a0, a9)
    SORT3(a2, a5, a8) CE(a8, a9)
}
__device__ __forceinline__ void sw9(float& a0, float& a1, float& a2, float& a3, float& a4,
                                    float& a5, float& a6, float& a7, float& a8) {
    SORT3(a0, a1, a2) SORT3(a3, a4, a5) SORT3(a6, a7, a8)
    SORT3(a0, a3, a6)
    SORT3(a2, a5, a8)
}
__device__ __forceinline__ void sw8(float& a0, float& a1, float& a2, float& a3, float& a4,
                                    float& a5, float& a6, float& a7) {
    SORT3(a0, a1, a2) SORT3(a3, a4, a5) CE(a6, a7)
    SORT3(a0, a3, a6)
    SORT3(a2, a5, a7)
}
__device__ __forceinline__ void sw7(float& a0, float& a1, float& a2, float& a3, float& a4,
                                    float& a5, float& a6) {
    SORT3(a0, a1, a2) SORT3(a3, a4, a5)
    SORT3(a0, a3, a6)
    SORT3(a2, a5, a6)
}
__device__ __forceinline__ void sw6(float& a0, float& a1, float& a2, float& a3, float& a4,
                                    float& a5) {
    SORT3(a0, a1, a2) SORT3(a3, a4, a5)
    CE(a0, a3)
    CE(a2, a5)
}

__device__ __forceinline__ float med5(float l0, float l1, float l2, float l3, float l4) {
    CE(l0, l1) CE(l2, l3)
    float a, b;
    asm("v_max_f32 %0, %1, %2" : "=v"(a) : "v"(l0), "v"(l2));
    asm("v_min_f32 %0, %1, %2" : "=v"(b) : "v"(l1), "v"(l3));
    return __builtin_amdgcn_fmed3f(a, b, l4);
}

// tail: 8 shared survivors + 5 private column values -> exact median of 25
__device__ __forceinline__ float tail5(float l1, float l2, float l3, float l4, float l5,
                                       float l6, float l7, float l8,
                                       float p0, float p1, float p2, float p3, float p4) {
    float l0 = p0;
    sw9(l0, l1, l2, l3, l4, l5, l6, l7, l8);
    l0 = p1;
    sw8(l0, l1, l2, l3, l4, l5, l6, l7);
    l0 = p2;
    sw7(l0, l1, l2, l3, l4, l5, l6);
    l0 = p3;
    sw6(l0, l1, l2, l3, l4, l5);
    l0 = p4;
    return med5(l0, l1, l2, l3, l4);
}

// shared forgetful phase over 20 elements -> middle 8 (by value)
__device__ __forceinline__ void shared20(float s0, float s1, float s2, float s3, float s4,
                                         float s5, float s6, float s7, float s8, float s9,
                                         float s10, float s11, float s12, float s13,
                                         float s14, float s15, float s16, float s17,
                                         float s18, float s19,
                                         float& o0, float& o1, float& o2, float& o3,
                                         float& o4, float& o5, float& o6, float& o7) {
    sw14(s0, s1, s2, s3, s4, s5, s6, s7, s8, s9, s10, s11, s12, s13);
    s0 = s14;
    sw13(s0, s1, s2, s3, s4, s5, s6, s7, s8, s9, s10, s11, s12);
    s0 = s15;
    sw12(s0, s1, s2, s3, s4, s5, s6, s7, s8, s9, s10, s11);
    s0 = s16;
    sw11(s0, s1, s2, s3, s4, s5, s6, s7, s8, s9, s10);
    s0 = s17;
    sw10(s0, s1, s2, s3, s4, s5, s6, s7, s8, s9);
    s0 = s18;
    sw9(s0, s1, s2, s3, s4, s5, s6, s7, s8);
    s0 = s19;
    o0 = s0; o1 = s1; o2 = s2; o3 = s3; o4 = s4; o5 = s5; o6 = s6; o7 = s7;
}

__global__ __launch_bounds__(256) void median5x5_tile(const float* __restrict__ img,
                                                      float* __restrict__ out) {
    __shared__ float lds[LR * LC];

    const int tx = threadIdx.x;        // 0..63 pair-column within tile
    const int ty = threadIdx.y;        // 0..3
    const int x0 = blockIdx.x * TW;    // tile origin (cols)
    const int y0 = blockIdx.y * TH;    // tile origin (rows)

    // ---- stage 20x132 halo tile into LDS (coalesced, reflected) ----
    const int tid = ty * 64 + tx;
#pragma unroll
    for (int k = 0; k < (LR * LC + 255) / 256; ++k) {
        const int i = tid + k * 256;
        if (i < LR * LC) {
            const int r = i / LC;
            const int c = i - r * LC;
            int gr = y0 - 2 + r;
            gr = (gr < 0) ? -gr : gr;
            gr = (gr >= IMG_H) ? 2 * IMG_H - 2 - gr : gr;
            int gc = x0 - 2 + c;
            gc = (gc < 0) ? -gc : gc;
            gc = (gc >= IMG_W) ? 2 * IMG_W - 2 - gc : gc;
            lds[i] = img[gr * IMG_W + gc];
        }
    }
    __syncthreads();

    // ---- compute 4 output rows per thread, 2 pixels each ----
    const int xL = x0 + 2 * tx;
    const float* wbase = lds + 2 * tx;  // window col 0 of this thread

#pragma unroll
    for (int s = 0; s < 4; ++s) {
        const int lr = ty * 4 + s;          // local output row -> lds rows lr..lr+4
        const float* p = wbase + lr * LC;

        // load the 5x6 window as float2 pairs (8B-aligned: 2*tx even, LC even)
        const float2 A01 = *(const float2*)(p + 0);
        const float2 A23 = *(const float2*)(p + 2);
        const float2 A45 = *(const float2*)(p + 4);
        const float2 B01 = *(const float2*)(p + LC + 0);
        const float2 B23 = *(const float2*)(p + LC + 2);
        const float2 B45 = *(const float2*)(p + LC + 4);
        const float2 C01 = *(const float2*)(p + 2 * LC + 0);
        const float2 C23 = *(const float2*)(p + 2 * LC + 2);
        const float2 C45 = *(const float2*)(p + 2 * LC + 4);
        const float2 D01 = *(const float2*)(p + 3 * LC + 0);
        const float2 D23 = *(const float2*)(p + 3 * LC + 2);
        const float2 D45 = *(const float2*)(p + 3 * LC + 4);
        const float2 E01 = *(const float2*)(p + 4 * LC + 0);
        const float2 E23 = *(const float2*)(p + 4 * LC + 2);
        const float2 E45 = *(const float2*)(p + 4 * LC + 4);

        // shared 20 = cols 1..4 x 5 rows
        float u0, u1, u2, u3, u4, u5, u6, u7;
        shared20(A01.y, A23.x, A23.y, A45.x,
                 B01.y, B23.x, B23.y, B45.x,
                 C01.y, C23.x, C23.y, C45.x,
                 D01.y, D23.x, D23.y, D45.x,
                 E01.y, E23.x, E23.y, E45.x,
                 u0, u1, u2, u3, u4, u5, u6, u7);

        const float mL = tail5(u0, u1, u2, u3, u4, u5, u6, u7,
                               A01.x, B01.x, C01.x, D01.x, E01.x);
        const float mR = tail5(u0, u1, u2, u3, u4, u5, u6, u7,
                               A45.y, B45.y, C45.y, D45.y, E45.y);

        *reinterpret_cast<float2*>(out + (y0 + lr) * IMG_W + xL) = make_float2(mL, mR);
    }
}

extern "C" void kernel_launch(void* const* d_in, const int* in_sizes, int n_in,
                              void* d_out, int out_size, void* d_ws, size_t ws_size,
                              hipStream_t stream) {
    const float* img = (const float*)d_in[0];
    float* out = (float*)d_out;
    dim3 block(64, 4);
    dim3 grid(IMG_W / TW, IMG_H / TH);
    median5x5_tile<<<grid, block, 0, stream>>>(img, out);
}